// Round 10
// baseline (373.682 us; speedup 1.0000x reference)
//
#include <hip/hip_runtime.h>
#include <math.h>

#define NEG_INF (-INFINITY)

typedef int      v4i __attribute__((ext_vector_type(4)));
typedef float    v4f __attribute__((ext_vector_type(4)));
typedef _Float16 v4h __attribute__((ext_vector_type(4)));

// fast log1mexp for v < 0: log(1 - e^v). Rel err ~1e-6.
__device__ __forceinline__ float fast_log1mexp(float v) {
    if (v > -0.125f) {
        float e = v * (1.0f + v * (0.5f + v * (0.16666667f + v * 0.041666667f)));
        return __logf(-e);
    }
    return __logf(1.0f - __expf(v));
}

// w (fp32) -> wh (fp16); regular stores (leave wh L2-warm for enc)
__global__ __launch_bounds__(256) void cvt_kernel(const float* __restrict__ w,
                                                  _Float16* __restrict__ wh, int n) {
    int i = blockIdx.x * blockDim.x + threadIdx.x;
    int n4 = n >> 2;
    if (i < n4) {
        v4f v = reinterpret_cast<const v4f*>(w)[i];
        v4h o;
        o.x = (_Float16)v.x; o.y = (_Float16)v.y;
        o.z = (_Float16)v.z; o.w = (_Float16)v.w;
        reinterpret_cast<v4h*>(wh)[i] = o;
    }
    int base = n4 << 2;
    if (i < (n - base)) wh[base + i] = (_Float16)w[base + i];
}

// encoded-x ptr -> clamped index into wh
__device__ __forceinline__ int widx(int p) { int j = (p >> 1) - 1; return j < 0 ? 0 : j; }
// fixup a raw gathered weight per ptr parity/constants
__device__ __forceinline__ float fixw(int p, float v) {
    float r = (p & 1) ? fast_log1mexp(v) : v;
    if (p < 2) r = (p == 0) ? NEG_INF : 0.0f;
    return r;
}

// Layer 0: product node fused with encode. 4 nodes/thread, straight-line.
__global__ __launch_bounds__(256) void sum4_enc_kernel(const _Float16* __restrict__ wh,
                                                       const v4i* __restrict__ ptrs,
                                                       _Float16* __restrict__ y, int n, int h) {
    int t = blockIdx.x * blockDim.x + threadIdx.x;
    if (t >= h) return;
    int i0 = t, i1 = t + h, i2 = t + 2 * h, i3 = t + 3 * h;
    int c1 = i1 < n ? i1 : 0, c2 = i2 < n ? i2 : 0, c3 = i3 < n ? i3 : 0;
    v4i p0 = __builtin_nontemporal_load(ptrs + i0);
    v4i p1 = __builtin_nontemporal_load(ptrs + c1);
    v4i p2 = __builtin_nontemporal_load(ptrs + c2);
    v4i p3 = __builtin_nontemporal_load(ptrs + c3);
    float g00 = (float)wh[widx(p0.x)], g01 = (float)wh[widx(p0.y)];
    float g02 = (float)wh[widx(p0.z)], g03 = (float)wh[widx(p0.w)];
    float g10 = (float)wh[widx(p1.x)], g11 = (float)wh[widx(p1.y)];
    float g12 = (float)wh[widx(p1.z)], g13 = (float)wh[widx(p1.w)];
    float g20 = (float)wh[widx(p2.x)], g21 = (float)wh[widx(p2.y)];
    float g22 = (float)wh[widx(p2.z)], g23 = (float)wh[widx(p2.w)];
    float g30 = (float)wh[widx(p3.x)], g31 = (float)wh[widx(p3.y)];
    float g32 = (float)wh[widx(p3.z)], g33 = (float)wh[widx(p3.w)];
    float s0 = (fixw(p0.x, g00) + fixw(p0.y, g01)) + (fixw(p0.z, g02) + fixw(p0.w, g03));
    float s1 = (fixw(p1.x, g10) + fixw(p1.y, g11)) + (fixw(p1.z, g12) + fixw(p1.w, g13));
    float s2 = (fixw(p2.x, g20) + fixw(p2.y, g21)) + (fixw(p2.z, g22) + fixw(p2.w, g23));
    float s3 = (fixw(p3.x, g30) + fixw(p3.y, g31)) + (fixw(p3.z, g32) + fixw(p3.w, g33));
    y[i0] = (_Float16)s0;              // regular stores: keep y0 L2-resident
    if (i1 < n) y[i1] = (_Float16)s1;
    if (i2 < n) y[i2] = (_Float16)s2;
    if (i3 < n) y[i3] = (_Float16)s3;
}

__device__ __forceinline__ float lse4(float a, float b, float c, float d) {
    float m = fmaxf(fmaxf(a, b), fmaxf(c, d));
    if (m == NEG_INF) return NEG_INF;       // all four -inf: ref yields -inf
    float s = __expf(a - m) + __expf(b - m) + __expf(c - m) + __expf(d - m) + 1e-15f;
    return __logf(s) + m;
}

// Layer 1: sum node (LSE), single pass, 2 nodes/thread, straight-line.
__global__ __launch_bounds__(256) void logsum4_h2h_kernel(const _Float16* __restrict__ x,
                                                          const v4i* __restrict__ ptrs,
                                                          _Float16* __restrict__ y, int n, int h) {
    int t = blockIdx.x * blockDim.x + threadIdx.x;
    if (t >= h) return;
    int i0 = t, i1 = t + h;
    int c1 = i1 < n ? i1 : 0;
    v4i p0 = __builtin_nontemporal_load(ptrs + i0);
    v4i p1 = __builtin_nontemporal_load(ptrs + c1);
    float a0 = (float)x[p0.x], b0 = (float)x[p0.y], e0 = (float)x[p0.z], d0 = (float)x[p0.w];
    float a1 = (float)x[p1.x], b1 = (float)x[p1.y], e1 = (float)x[p1.z], d1 = (float)x[p1.w];
    float s0 = lse4(a0, b0, e0, d0);
    float s1 = lse4(a1, b1, e1, d1);
    y[i0] = (_Float16)s0;
    if (i1 < n) y[i1] = (_Float16)s1;
}

// Layer 2: product node, 2 nodes/thread, straight-line.
__global__ __launch_bounds__(256) void sum4_h2h_kernel(const _Float16* __restrict__ x,
                                                       const v4i* __restrict__ ptrs,
                                                       _Float16* __restrict__ y, int n, int h) {
    int t = blockIdx.x * blockDim.x + threadIdx.x;
    if (t >= h) return;
    int i0 = t, i1 = t + h;
    int c1 = i1 < n ? i1 : 0;
    v4i p0 = __builtin_nontemporal_load(ptrs + i0);
    v4i p1 = __builtin_nontemporal_load(ptrs + c1);
    float s0 = ((float)x[p0.x] + (float)x[p0.y]) + ((float)x[p0.z] + (float)x[p0.w]);
    float s1 = ((float)x[p1.x] + (float)x[p1.y]) + ((float)x[p1.z] + (float)x[p1.w]);
    y[i0] = (_Float16)s0;
    if (i1 < n) y[i1] = (_Float16)s1;
}

// Layer 3: final sum node, fp16 gather -> fp32 out, 1 node/thread.
__global__ __launch_bounds__(256) void logsum4_h2f_kernel(const _Float16* __restrict__ x,
                                                          const v4i* __restrict__ ptrs,
                                                          float* __restrict__ y, int n) {
    int t = blockIdx.x * blockDim.x + threadIdx.x;
    if (t >= n) return;
    v4i p = __builtin_nontemporal_load(ptrs + t);
    float r = lse4((float)x[p.x], (float)x[p.y], (float)x[p.z], (float)x[p.w]);
    __builtin_nontemporal_store(r, y + t);
}

extern "C" void kernel_launch(void* const* d_in, const int* in_sizes, int n_in,
                              void* d_out, int out_size, void* d_ws, size_t ws_size,
                              hipStream_t stream) {
    // d_in dict order: weights, ptrs0, csr0, n0, ptrs1, csr1, n1, ptrs2, csr2, n2, ptrs3, csr3, n3
    const float* w     = (const float*)d_in[0];
    const v4i*   ptrs0 = (const v4i*)d_in[1];
    const v4i*   ptrs1 = (const v4i*)d_in[4];
    const v4i*   ptrs2 = (const v4i*)d_in[7];
    const v4i*   ptrs3 = (const v4i*)d_in[10];

    const int n_vars = in_sizes[0];
    const int n0 = in_sizes[1] / 4;
    const int n1 = in_sizes[4] / 4;
    const int n2 = in_sizes[7] / 4;
    const int n3 = in_sizes[10] / 4;

    // workspace layout (256B-aligned), intermediates fp16
    char* ws = (char*)d_ws;
    size_t off = 0;
    _Float16* wh = (_Float16*)(ws + off); off += ((size_t)n_vars * 2 + 255) & ~(size_t)255;
    _Float16* y0 = (_Float16*)(ws + off); off += ((size_t)n0 * 2 + 255) & ~(size_t)255;
    _Float16* y1 = (_Float16*)(ws + off); off += ((size_t)n1 * 2 + 255) & ~(size_t)255;
    _Float16* y2 = (_Float16*)(ws + off);
    float* out = (float*)d_out;

    const int B = 256;
    int hc = (n_vars + 3) / 4;
    int h0 = (n0 + 3) / 4;                 // enc: 4 nodes/thread
    int h1 = (n1 + 1) / 2;                 // l1: 2 nodes/thread
    int h2 = (n2 + 1) / 2;                 // l2: 2 nodes/thread

    cvt_kernel        <<<(hc + B - 1) / B, B, 0, stream>>>(w, wh, n_vars);
    sum4_enc_kernel   <<<(h0 + B - 1) / B, B, 0, stream>>>(wh, ptrs0, y0, n0, h0);
    logsum4_h2h_kernel<<<(h1 + B - 1) / B, B, 0, stream>>>(y0, ptrs1, y1, n1, h1);
    sum4_h2h_kernel   <<<(h2 + B - 1) / B, B, 0, stream>>>(y1, ptrs2, y2, n2, h2);
    logsum4_h2f_kernel<<<(n3 + B - 1) / B, B, 0, stream>>>(y2, ptrs3, out, n3);
}

// Round 11
// 358.567 us; speedup vs baseline: 1.0422x; 1.0422x over previous
//
#include <hip/hip_runtime.h>
#include <math.h>

#define NEG_INF (-INFINITY)

typedef int      v4i __attribute__((ext_vector_type(4)));
typedef float    v4f __attribute__((ext_vector_type(4)));
typedef _Float16 v4h __attribute__((ext_vector_type(4)));

// fast log1mexp for v < 0: log(1 - e^v). Rel err ~1e-6.
__device__ __forceinline__ float fast_log1mexp(float v) {
    if (v > -0.125f) {
        float e = v * (1.0f + v * (0.5f + v * (0.16666667f + v * 0.041666667f)));
        return __logf(-e);
    }
    return __logf(1.0f - __expf(v));
}

// w (fp32) -> wh (fp16)
__global__ __launch_bounds__(256) void cvt_kernel(const float* __restrict__ w,
                                                  _Float16* __restrict__ wh, int n) {
    int i = blockIdx.x * blockDim.x + threadIdx.x;
    int n4 = n >> 2;
    if (i < n4) {
        v4f v = reinterpret_cast<const v4f*>(w)[i];
        v4h o;
        o.x = (_Float16)v.x; o.y = (_Float16)v.y;
        o.z = (_Float16)v.z; o.w = (_Float16)v.w;
        reinterpret_cast<v4h*>(wh)[i] = o;
    }
    int base = n4 << 2;
    if (i < (n - base)) wh[base + i] = (_Float16)w[base + i];
}

// encoded-x ptr -> clamped index into wh
__device__ __forceinline__ int widx(int p) { int j = (p >> 1) - 1; return j < 0 ? 0 : j; }
// fixup a raw gathered weight per ptr parity/constants
__device__ __forceinline__ float fixw(int p, float v) {
    float r = (p & 1) ? fast_log1mexp(v) : v;
    if (p < 2) r = (p == 0) ? NEG_INF : 0.0f;
    return r;
}

// Layer 0: product node fused with encode. 4 nodes/thread, straight-line.
// Launched twice on half ranges (visibility probe: lowers top-5 threshold).
__global__ __launch_bounds__(256) void sum4_enc_kernel(const _Float16* __restrict__ wh,
                                                       const v4i* __restrict__ ptrs,
                                                       _Float16* __restrict__ y, int n, int h) {
    int t = blockIdx.x * blockDim.x + threadIdx.x;
    if (t >= h) return;
    int i0 = t, i1 = t + h, i2 = t + 2 * h, i3 = t + 3 * h;
    int c1 = i1 < n ? i1 : 0, c2 = i2 < n ? i2 : 0, c3 = i3 < n ? i3 : 0;
    v4i p0 = __builtin_nontemporal_load(ptrs + i0);
    v4i p1 = __builtin_nontemporal_load(ptrs + c1);
    v4i p2 = __builtin_nontemporal_load(ptrs + c2);
    v4i p3 = __builtin_nontemporal_load(ptrs + c3);
    float g00 = (float)wh[widx(p0.x)], g01 = (float)wh[widx(p0.y)];
    float g02 = (float)wh[widx(p0.z)], g03 = (float)wh[widx(p0.w)];
    float g10 = (float)wh[widx(p1.x)], g11 = (float)wh[widx(p1.y)];
    float g12 = (float)wh[widx(p1.z)], g13 = (float)wh[widx(p1.w)];
    float g20 = (float)wh[widx(p2.x)], g21 = (float)wh[widx(p2.y)];
    float g22 = (float)wh[widx(p2.z)], g23 = (float)wh[widx(p2.w)];
    float g30 = (float)wh[widx(p3.x)], g31 = (float)wh[widx(p3.y)];
    float g32 = (float)wh[widx(p3.z)], g33 = (float)wh[widx(p3.w)];
    float s0 = (fixw(p0.x, g00) + fixw(p0.y, g01)) + (fixw(p0.z, g02) + fixw(p0.w, g03));
    float s1 = (fixw(p1.x, g10) + fixw(p1.y, g11)) + (fixw(p1.z, g12) + fixw(p1.w, g13));
    float s2 = (fixw(p2.x, g20) + fixw(p2.y, g21)) + (fixw(p2.z, g22) + fixw(p2.w, g23));
    float s3 = (fixw(p3.x, g30) + fixw(p3.y, g31)) + (fixw(p3.z, g32) + fixw(p3.w, g33));
    __builtin_nontemporal_store((_Float16)s0, y + i0);
    if (i1 < n) __builtin_nontemporal_store((_Float16)s1, y + i1);
    if (i2 < n) __builtin_nontemporal_store((_Float16)s2, y + i2);
    if (i3 < n) __builtin_nontemporal_store((_Float16)s3, y + i3);
}

// partial stable LSE (no epsilon): -inf if all inputs -inf.
__device__ __forceinline__ float plse4(float a, float b, float c, float d) {
    float m = fmaxf(fmaxf(a, b), fmaxf(c, d));
    if (m == NEG_INF) return NEG_INF;
    float s = __expf(a - m) + __expf(b - m) + __expf(c - m) + __expf(d - m);
    return __logf(s) + m;
}

// Layer 1 pass A: predicated gathers from the L2-resident lower half of y0.
__global__ __launch_bounds__(256) void l1a_kernel(const _Float16* __restrict__ x,
                                                  const v4i* __restrict__ ptrs,
                                                  _Float16* __restrict__ LA,
                                                  int n, int h, int half) {
    int t = blockIdx.x * blockDim.x + threadIdx.x;
    if (t >= h) return;
    int i0 = t, i1 = t + h;
    int c1 = i1 < n ? i1 : 0;
    v4i p0 = __builtin_nontemporal_load(ptrs + i0);
    v4i p1 = __builtin_nontemporal_load(ptrs + c1);
    float a0 = NEG_INF, b0 = NEG_INF, e0 = NEG_INF, d0 = NEG_INF;
    float a1 = NEG_INF, b1 = NEG_INF, e1 = NEG_INF, d1 = NEG_INF;
    if (p0.x < half) a0 = (float)x[p0.x];
    if (p0.y < half) b0 = (float)x[p0.y];
    if (p0.z < half) e0 = (float)x[p0.z];
    if (p0.w < half) d0 = (float)x[p0.w];
    if (p1.x < half) a1 = (float)x[p1.x];
    if (p1.y < half) b1 = (float)x[p1.y];
    if (p1.z < half) e1 = (float)x[p1.z];
    if (p1.w < half) d1 = (float)x[p1.w];
    float s0 = plse4(a0, b0, e0, d0);
    float s1 = plse4(a1, b1, e1, d1);
    __builtin_nontemporal_store((_Float16)s0, LA + i0);
    if (i1 < n) __builtin_nontemporal_store((_Float16)s1, LA + i1);
}

// exact two-way LSE merge (epsilon once, matching ref)
__device__ __forceinline__ float merge_lse(float LA, float LB) {
    float m = fmaxf(LA, LB);
    if (m == NEG_INF) return NEG_INF;
    float s = __expf(LA - m) + __expf(LB - m) + 1e-15f;
    return __logf(s) + m;
}

// Layer 1 pass B: upper-half gathers + merge.
__global__ __launch_bounds__(256) void l1b_kernel(const _Float16* __restrict__ x,
                                                  const v4i* __restrict__ ptrs,
                                                  const _Float16* __restrict__ LA,
                                                  _Float16* __restrict__ y,
                                                  int n, int h, int half) {
    int t = blockIdx.x * blockDim.x + threadIdx.x;
    if (t >= h) return;
    int i0 = t, i1 = t + h;
    int c1 = i1 < n ? i1 : 0;
    v4i p0 = __builtin_nontemporal_load(ptrs + i0);
    v4i p1 = __builtin_nontemporal_load(ptrs + c1);
    float la0 = (float)__builtin_nontemporal_load(LA + i0);
    float la1 = (float)__builtin_nontemporal_load(LA + c1);
    float a0 = NEG_INF, b0 = NEG_INF, e0 = NEG_INF, d0 = NEG_INF;
    float a1 = NEG_INF, b1 = NEG_INF, e1 = NEG_INF, d1 = NEG_INF;
    if (p0.x >= half) a0 = (float)x[p0.x];
    if (p0.y >= half) b0 = (float)x[p0.y];
    if (p0.z >= half) e0 = (float)x[p0.z];
    if (p0.w >= half) d0 = (float)x[p0.w];
    if (p1.x >= half) a1 = (float)x[p1.x];
    if (p1.y >= half) b1 = (float)x[p1.y];
    if (p1.z >= half) e1 = (float)x[p1.z];
    if (p1.w >= half) d1 = (float)x[p1.w];
    float s0 = merge_lse(la0, plse4(a0, b0, e0, d0));
    float s1 = merge_lse(la1, plse4(a1, b1, e1, d1));
    __builtin_nontemporal_store((_Float16)s0, y + i0);
    if (i1 < n) __builtin_nontemporal_store((_Float16)s1, y + i1);
}

// Product node (layer 2): 2 nodes/thread.
__global__ __launch_bounds__(256) void sum4_h2h_kernel(const _Float16* __restrict__ x,
                                                       const v4i* __restrict__ ptrs,
                                                       _Float16* __restrict__ y, int n, int h) {
    int t = blockIdx.x * blockDim.x + threadIdx.x;
    if (t >= h) return;
    int i0 = t, i1 = t + h;
    int c1 = i1 < n ? i1 : 0;
    v4i p0 = __builtin_nontemporal_load(ptrs + i0);
    v4i p1 = __builtin_nontemporal_load(ptrs + c1);
    float s0 = ((float)x[p0.x] + (float)x[p0.y]) + ((float)x[p0.z] + (float)x[p0.w]);
    float s1 = ((float)x[p1.x] + (float)x[p1.y]) + ((float)x[p1.z] + (float)x[p1.w]);
    __builtin_nontemporal_store((_Float16)s0, y + i0);
    if (i1 < n) __builtin_nontemporal_store((_Float16)s1, y + i1);
}

__device__ __forceinline__ float lse4(float a, float b, float c, float d) {
    float m = fmaxf(fmaxf(a, b), fmaxf(c, d));
    if (m == NEG_INF) return NEG_INF;
    float s = __expf(a - m) + __expf(b - m) + __expf(c - m) + __expf(d - m) + 1e-15f;
    return __logf(s) + m;
}

// Final sum node (layer 3): 1 node/thread.
__global__ __launch_bounds__(256) void logsum4_h2f_kernel(const _Float16* __restrict__ x,
                                                          const v4i* __restrict__ ptrs,
                                                          float* __restrict__ y, int n) {
    int t = blockIdx.x * blockDim.x + threadIdx.x;
    if (t >= n) return;
    v4i p = __builtin_nontemporal_load(ptrs + t);
    float r = lse4((float)x[p.x], (float)x[p.y], (float)x[p.z], (float)x[p.w]);
    __builtin_nontemporal_store(r, y + t);
}

extern "C" void kernel_launch(void* const* d_in, const int* in_sizes, int n_in,
                              void* d_out, int out_size, void* d_ws, size_t ws_size,
                              hipStream_t stream) {
    // d_in dict order: weights, ptrs0, csr0, n0, ptrs1, csr1, n1, ptrs2, csr2, n2, ptrs3, csr3, n3
    const float* w     = (const float*)d_in[0];
    const v4i*   ptrs0 = (const v4i*)d_in[1];
    const v4i*   ptrs1 = (const v4i*)d_in[4];
    const v4i*   ptrs2 = (const v4i*)d_in[7];
    const v4i*   ptrs3 = (const v4i*)d_in[10];

    const int n_vars = in_sizes[0];
    const int n0 = in_sizes[1] / 4;
    const int n1 = in_sizes[4] / 4;
    const int n2 = in_sizes[7] / 4;
    const int n3 = in_sizes[10] / 4;

    // workspace layout (256B-aligned), intermediates fp16
    char* ws = (char*)d_ws;
    size_t off = 0;
    _Float16* wh = (_Float16*)(ws + off); off += ((size_t)n_vars * 2 + 255) & ~(size_t)255;
    _Float16* y0 = (_Float16*)(ws + off); off += ((size_t)n0 * 2 + 255) & ~(size_t)255;
    _Float16* y1 = (_Float16*)(ws + off); off += ((size_t)n1 * 2 + 255) & ~(size_t)255;
    _Float16* y2 = (_Float16*)(ws + off); off += ((size_t)n2 * 2 + 255) & ~(size_t)255;
    _Float16* LA = (_Float16*)(ws + off);
    float* out = (float*)d_out;

    const int B = 256;
    int hc = (n_vars + 3) / 4;
    int nEa = n0 / 2;                      // enc first half (node count)
    int nEb = n0 - nEa;                    // enc second half
    int hEa = (nEa + 3) / 4, hEb = (nEb + 3) / 4;
    int h1 = (n1 + 1) / 2;                 // l1a/l1b: 2 nodes/thread
    int h2 = (n2 + 1) / 2;                 // l2: 2 nodes/thread
    int half0 = n0 / 2;                    // 4 MB fp16 boundary of y0

    cvt_kernel        <<<(hc + B - 1) / B, B, 0, stream>>>(w, wh, n_vars);
    sum4_enc_kernel   <<<(hEa + B - 1) / B, B, 0, stream>>>(wh, ptrs0,       y0,       nEa, hEa);
    sum4_enc_kernel   <<<(hEb + B - 1) / B, B, 0, stream>>>(wh, ptrs0 + nEa, y0 + nEa, nEb, hEb);
    l1a_kernel        <<<(h1 + B - 1) / B, B, 0, stream>>>(y0, ptrs1, LA, n1, h1, half0);
    l1b_kernel        <<<(h1 + B - 1) / B, B, 0, stream>>>(y0, ptrs1, LA, y1, n1, h1, half0);
    sum4_h2h_kernel   <<<(h2 + B - 1) / B, B, 0, stream>>>(y1, ptrs2, y2, n2, h2);
    logsum4_h2f_kernel<<<(n3 + B - 1) / B, B, 0, stream>>>(y2, ptrs3, out, n3);
}